// Round 11
// baseline (537.528 us; speedup 1.0000x reference)
//
#include <hip/hip_runtime.h>
#include <cstdint>

// TGN memory update: message scatter-mean (bf16 packed atomics) + MFMA GRU.
// Round 11: M=64, weights streamed L2->VGPR (even/odd dbuf, full unroll),
// NO barriers in main loop (disjoint wave tiles, read-only Xf). 8 waves/CU.

#define MEMD 128
#define ACCD 384
#define MSGD 512

typedef __attribute__((ext_vector_type(8))) short bf16x8;
typedef __attribute__((ext_vector_type(2))) short bf16x2;
typedef __attribute__((ext_vector_type(4))) float f32x4;

static __device__ __forceinline__ short f2bf(float f) {
    uint32_t u = __builtin_bit_cast(uint32_t, f);
    u = (u + 0x7FFFu + ((u >> 16) & 1u)) >> 16;
    return (short)u;
}
static __device__ __forceinline__ float bf2f(short s) {
    return __builtin_bit_cast(float, ((uint32_t)(uint16_t)s) << 16);
}
static __device__ __forceinline__ void atomic_pk_add_bf16(short* p, bf16x2 v) {
    const uint64_t addr = (uint64_t)p;
    asm volatile("global_atomic_pk_add_bf16 %0, %1, off" :: "v"(addr), "v"(v) : "memory");
}

// ---------------- Prep A: memory f32 -> bf16 ----------------
__global__ __launch_bounds__(256) void tgn_prep_mem(
    const float* __restrict__ mem, short* __restrict__ memB, int n8)
{
    const int i = blockIdx.x * 256 + threadIdx.x;
    if (i >= n8) return;
    const float4 a = *reinterpret_cast<const float4*>(mem + (size_t)i * 8);
    const float4 b = *reinterpret_cast<const float4*>(mem + (size_t)i * 8 + 4);
    bf16x8 v;
    v[0] = f2bf(a.x); v[1] = f2bf(a.y); v[2] = f2bf(a.z); v[3] = f2bf(a.w);
    v[4] = f2bf(b.x); v[5] = f2bf(b.y); v[6] = f2bf(b.z); v[7] = f2bf(b.w);
    *reinterpret_cast<bf16x8*>(memB + (size_t)i * 8) = v;
}

// ---------------- Prep B: weights f32 -> bf16 frag-major ----------------
// Wb: gi frags [24 ntile][16 kstep][64 lane], then gh frags [24][4][64].
// Frag (n,ks,lane): j = n*16 + (lane&15), k = ks*32 + (lane>>4)*8 .. +7.
#define GI_SLOTS (24 * 16 * 64)
#define GH_SLOTS (24 * 4 * 64)

__global__ __launch_bounds__(256) void tgn_prep_w(
    const float* __restrict__ W_ih, const float* __restrict__ W_hh,
    bf16x8* __restrict__ Wb)
{
    const int s = blockIdx.x * 256 + threadIdx.x;
    if (s >= GI_SLOTS + GH_SLOTS) return;
    const float* src;
    if (s < GI_SLOTS) {
        const int n = s / (16 * 64), rem = s % (16 * 64);
        const int ks = rem / 64, l = rem % 64;
        const int j = n * 16 + (l & 15), k = ks * 32 + (l >> 4) * 8;
        src = W_ih + (size_t)j * MSGD + k;
    } else {
        const int s2 = s - GI_SLOTS;
        const int n = s2 / (4 * 64), rem = s2 % (4 * 64);
        const int ks = rem / 64, l = rem % 64;
        const int j = n * 16 + (l & 15), k = ks * 32 + (l >> 4) * 8;
        src = W_hh + (size_t)j * MEMD + k;
    }
    bf16x8 v;
    #pragma unroll
    for (int e = 0; e < 8; ++e) v[e] = f2bf(src[e]);
    Wb[s] = v;
}

// ---------------- Phase 1: per-event scatter (packed bf16 atomics) --------
__global__ __launch_bounds__(256) void tgn_scatter(
    const short* __restrict__ memB, const int* __restrict__ last_update,
    const int* __restrict__ src, const int* __restrict__ dst, const int* __restrict__ t,
    const float* __restrict__ raw_msg, const float* __restrict__ time_w,
    const float* __restrict__ time_b,
    short* __restrict__ ACC, int* __restrict__ cnt, int* __restrict__ lu_new,
    int n_events)
{
    const int e = blockIdx.x * 4 + (threadIdx.x >> 6);
    if (e >= n_events) return;
    const int l = threadIdx.x & 63;
    const int j0 = l * 2;

    const int s = src[e];
    const int d = dst[e];
    const int te = t[e];

    const float2 tw = *reinterpret_cast<const float2*>(time_w + j0);
    const float2 tb = *reinterpret_cast<const float2*>(time_b + j0);
    const float dts = (float)(te - last_update[s]);
    const float dtd = (float)(te - last_update[d]);
    bf16x2 tenc_s, tenc_d, rb;
    tenc_s[0] = f2bf(__cosf(fmaf(dts, tw.x, tb.x)));
    tenc_s[1] = f2bf(__cosf(fmaf(dts, tw.y, tb.y)));
    tenc_d[0] = f2bf(__cosf(fmaf(dtd, tw.x, tb.x)));
    tenc_d[1] = f2bf(__cosf(fmaf(dtd, tw.y, tb.y)));

    const bf16x2 ms2 = *reinterpret_cast<const bf16x2*>(memB + (size_t)s * MEMD + j0);
    const bf16x2 md2 = *reinterpret_cast<const bf16x2*>(memB + (size_t)d * MEMD + j0);
    const float2 rw = *reinterpret_cast<const float2*>(raw_msg + (size_t)e * MEMD + j0);
    rb[0] = f2bf(rw.x); rb[1] = f2bf(rw.y);

    short* As = ACC + (size_t)s * ACCD;
    short* Ad = ACC + (size_t)d * ACCD;
    atomic_pk_add_bf16(As + j0, md2);
    atomic_pk_add_bf16(As + 128 + j0, rb);
    atomic_pk_add_bf16(As + 256 + j0, tenc_s);
    atomic_pk_add_bf16(Ad + j0, ms2);
    atomic_pk_add_bf16(Ad + 128 + j0, rb);
    atomic_pk_add_bf16(Ad + 256 + j0, tenc_d);

    if (l == 0) {
        atomicAdd(cnt + s, 1);
        atomicAdd(cnt + d, 1);
        atomicMax(lu_new + s, te);
        atomicMax(lu_new + d, te);
    }
}

// ---------------- Phase 2: MFMA GEMM + GRU (free-running waves) -----------
// 512 threads (8 waves), 64 nodes/block, 64 KB LDS (Xf only).
// Wave wv owns N-tile triple {wv, wv+8, wv+16} -> (j, j+128, j+256);
// B-frags streamed L2->VGPR with even/odd buffers, no block sync in loop.
#define MFMA12(ACCA, BV, A0, A1, A2, A3)                                        \
    ACCA[0] = __builtin_amdgcn_mfma_f32_16x16x32_bf16(A0, BV, ACCA[0], 0, 0, 0); \
    ACCA[1] = __builtin_amdgcn_mfma_f32_16x16x32_bf16(A1, BV, ACCA[1], 0, 0, 0); \
    ACCA[2] = __builtin_amdgcn_mfma_f32_16x16x32_bf16(A2, BV, ACCA[2], 0, 0, 0); \
    ACCA[3] = __builtin_amdgcn_mfma_f32_16x16x32_bf16(A3, BV, ACCA[3], 0, 0, 0);

__global__ __launch_bounds__(512, 2) void tgn_gru_mfma(
    const short* __restrict__ memB, const short* __restrict__ ACC,
    const int* __restrict__ cnt, const bf16x8* __restrict__ Wb,
    const float* __restrict__ b_ih, const float* __restrict__ b_hh,
    float* __restrict__ out, int n_nodes)
{
    __shared__ bf16x8 Xf[4 * 16 * 64];      // 64 KB : X tile (frag-major)
    ushort* Xh = reinterpret_cast<ushort*>(Xf);
    float*  Sout = reinterpret_cast<float*>(Xf);   // reused after mv reads

    const int tid = threadIdx.x;
    const int lane = tid & 63;
    const int wv = tid >> 6;                 // wave id 0..7 (uniform)
    const int node0 = blockIdx.x * 64;

    // ---- stage X tile: issue all 8 loads, then convert ----
    bf16x8 sraw[8];
    float  sinv[8];
    #pragma unroll
    for (int i = 0; i < 8; ++i) {
        const int slot = i * 512 + tid;      // 0..4095
        const int l = slot & 63;
        const int ks = (slot >> 6) & 15;
        const int m = slot >> 10;            // 0..3
        int node = node0 + m * 16 + (l & 15);
        if (node >= n_nodes) node = n_nodes - 1;
        const int kbase = ks * 32 + (l >> 4) * 8;
        if (kbase < 128) {
            sraw[i] = *reinterpret_cast<const bf16x8*>(memB + (size_t)node * MEMD + kbase);
            sinv[i] = -1.0f;
        } else {
            sraw[i] = *reinterpret_cast<const bf16x8*>(ACC + (size_t)node * ACCD + (kbase - 128));
            const int c = cnt[node];
            sinv[i] = (c > 0) ? 1.0f / (float)c : 0.0f;
        }
    }
    #pragma unroll
    for (int i = 0; i < 8; ++i) {
        const int slot = i * 512 + tid;
        bf16x8 xv = sraw[i];
        if (sinv[i] >= 0.0f) {
            #pragma unroll
            for (int e2 = 0; e2 < 8; ++e2) xv[e2] = f2bf(bf2f(xv[e2]) * sinv[i]);
        }
        Xf[slot] = xv;
    }
    __syncthreads();   // X visible; waves run free from here

    const int col = lane & 15;
    const int rgrp = lane >> 4;

    f32x4 acc_i[3][4], acc_h[3][4];
    #pragma unroll
    for (int c = 0; c < 3; ++c)
        #pragma unroll
        for (int m = 0; m < 4; ++m) {
            acc_i[c][m] = (f32x4){0.f, 0.f, 0.f, 0.f};
            acc_h[c][m] = (f32x4){0.f, 0.f, 0.f, 0.f};
        }

    const bf16x8* __restrict__ Wh = Wb + GI_SLOTS;
    const int n0 = wv, n1 = wv + 8, n2 = wv + 16;

    bf16x8 e0, e1, e2;   // even-step B buffers
    bf16x8 o0, o1, o2;   // odd-step B buffers
    e0 = Wh[(n0 * 4 + 0) * 64 + lane];
    e1 = Wh[(n1 * 4 + 0) * 64 + lane];
    e2 = Wh[(n2 * 4 + 0) * 64 + lane];

    // ---- gh: K=128, k-steps 0..3 ----
    #pragma unroll
    for (int kp = 0; kp < 2; ++kp) {
        const int ks = kp * 2;
        o0 = Wh[(n0 * 4 + ks + 1) * 64 + lane];
        o1 = Wh[(n1 * 4 + ks + 1) * 64 + lane];
        o2 = Wh[(n2 * 4 + ks + 1) * 64 + lane];
        {
            const bf16x8 a0 = Xf[(0 * 16 + ks) * 64 + lane];
            const bf16x8 a1 = Xf[(1 * 16 + ks) * 64 + lane];
            const bf16x8 a2 = Xf[(2 * 16 + ks) * 64 + lane];
            const bf16x8 a3 = Xf[(3 * 16 + ks) * 64 + lane];
            MFMA12(acc_h[0], e0, a0, a1, a2, a3)
            MFMA12(acc_h[1], e1, a0, a1, a2, a3)
            MFMA12(acc_h[2], e2, a0, a1, a2, a3)
        }
        if (ks + 2 < 4) {
            e0 = Wh[(n0 * 4 + ks + 2) * 64 + lane];
            e1 = Wh[(n1 * 4 + ks + 2) * 64 + lane];
            e2 = Wh[(n2 * 4 + ks + 2) * 64 + lane];
        } else {
            e0 = Wb[(n0 * 16 + 0) * 64 + lane];
            e1 = Wb[(n1 * 16 + 0) * 64 + lane];
            e2 = Wb[(n2 * 16 + 0) * 64 + lane];
        }
        {
            const bf16x8 a0 = Xf[(0 * 16 + ks + 1) * 64 + lane];
            const bf16x8 a1 = Xf[(1 * 16 + ks + 1) * 64 + lane];
            const bf16x8 a2 = Xf[(2 * 16 + ks + 1) * 64 + lane];
            const bf16x8 a3 = Xf[(3 * 16 + ks + 1) * 64 + lane];
            MFMA12(acc_h[0], o0, a0, a1, a2, a3)
            MFMA12(acc_h[1], o1, a0, a1, a2, a3)
            MFMA12(acc_h[2], o2, a0, a1, a2, a3)
        }
    }

    // ---- gi: K=512, k-steps 0..15 (e* holds ks0) ----
    #pragma unroll
    for (int kp = 0; kp < 8; ++kp) {
        const int ks = kp * 2;
        o0 = Wb[(n0 * 16 + ks + 1) * 64 + lane];
        o1 = Wb[(n1 * 16 + ks + 1) * 64 + lane];
        o2 = Wb[(n2 * 16 + ks + 1) * 64 + lane];
        {
            const bf16x8 a0 = Xf[(0 * 16 + ks) * 64 + lane];
            const bf16x8 a1 = Xf[(1 * 16 + ks) * 64 + lane];
            const bf16x8 a2 = Xf[(2 * 16 + ks) * 64 + lane];
            const bf16x8 a3 = Xf[(3 * 16 + ks) * 64 + lane];
            MFMA12(acc_i[0], e0, a0, a1, a2, a3)
            MFMA12(acc_i[1], e1, a0, a1, a2, a3)
            MFMA12(acc_i[2], e2, a0, a1, a2, a3)
        }
        if (ks + 2 < 16) {
            e0 = Wb[(n0 * 16 + ks + 2) * 64 + lane];
            e1 = Wb[(n1 * 16 + ks + 2) * 64 + lane];
            e2 = Wb[(n2 * 16 + ks + 2) * 64 + lane];
        }
        {
            const bf16x8 a0 = Xf[(0 * 16 + ks + 1) * 64 + lane];
            const bf16x8 a1 = Xf[(1 * 16 + ks + 1) * 64 + lane];
            const bf16x8 a2 = Xf[(2 * 16 + ks + 1) * 64 + lane];
            const bf16x8 a3 = Xf[(3 * 16 + ks + 1) * 64 + lane];
            MFMA12(acc_i[0], o0, a0, a1, a2, a3)
            MFMA12(acc_i[1], o1, a0, a1, a2, a3)
            MFMA12(acc_i[2], o2, a0, a1, a2, a3)
        }
    }

    // ---- GRU epilogue: wave-local triple (j, j+128, j+256) ----
    uint32_t hmask = 0;
    #pragma unroll
    for (int m = 0; m < 4; ++m)
        #pragma unroll
        for (int r = 0; r < 4; ++r) {
            const int node = node0 + m * 16 + rgrp * 4 + r;
            if (node < n_nodes && cnt[node] > 0) hmask |= 1u << (m * 4 + r);
        }

    const int jr = wv * 16 + col;            // 0..127
    const float bir = b_ih[jr], biz = b_ih[jr + 128], bin = b_ih[jr + 256];
    const float bhr = b_hh[jr], bhz = b_hh[jr + 128], bhn = b_hh[jr + 256];
    const int ksj = jr >> 5;
    const int sub = ((jr >> 3) & 3) * 16;
    const int elem = jr & 7;

    float rout[4][4];
    #pragma unroll
    for (int m = 0; m < 4; ++m) {
        #pragma unroll
        for (int r = 0; r < 4; ++r) {
            const bool has = (hmask >> (m * 4 + r)) & 1;
            const float gir = (has ? acc_i[0][m][r] : 0.f) + bir;
            const float giz = (has ? acc_i[1][m][r] : 0.f) + biz;
            const float gin = (has ? acc_i[2][m][r] : 0.f) + bin;
            const float ghr = acc_h[0][m][r] + bhr;
            const float ghz = acc_h[1][m][r] + bhz;
            const float ghn = acc_h[2][m][r] + bhn;
            const float rr = __fdividef(1.0f, 1.0f + __expf(-(gir + ghr)));
            const float zz = __fdividef(1.0f, 1.0f + __expf(-(giz + ghz)));
            const float targ = fmaf(rr, ghn, gin);
            const float e2v = __expf(2.0f * targ);
            const float nn = __fdividef(e2v - 1.0f, e2v + 1.0f);
            const int slot = (m * 16 + ksj) * 64 + sub + (rgrp * 4 + r);
            const float mv = bf2f((short)Xh[slot * 8 + elem]);
            rout[m][r] = (1.0f - zz) * nn + zz * mv;
        }
    }
    __syncthreads();   // all waves done with Xf (mv) -> reuse as Sout

    #pragma unroll
    for (int m = 0; m < 4; ++m)
        #pragma unroll
        for (int r = 0; r < 4; ++r)
            Sout[(m * 16 + rgrp * 4 + r) * MEMD + jr] = rout[m][r];
    __syncthreads();

    // ---- fully-coalesced float4 write-out (64 nodes x 128 f32) ----
    float4* out4 = reinterpret_cast<float4*>(out + (size_t)node0 * MEMD);
    const float4* S4 = reinterpret_cast<const float4*>(Sout);
    if (node0 + 64 <= n_nodes) {
        #pragma unroll
        for (int it = 0; it < 4; ++it)
            out4[it * 512 + tid] = S4[it * 512 + tid];
    } else {
        #pragma unroll
        for (int it = 0; it < 4; ++it) {
            const int idx = it * 512 + tid;
            if (node0 + (idx >> 5) < n_nodes) out4[idx] = S4[idx];
        }
    }
}

// ---------------- Phase 3: last_update -> float out ----------------
__global__ void tgn_lu_out(const int* __restrict__ lu, float* __restrict__ out2, int n_nodes)
{
    const int i = blockIdx.x * blockDim.x + threadIdx.x;
    if (i < n_nodes) out2[i] = (float)lu[i];
}

extern "C" void kernel_launch(void* const* d_in, const int* in_sizes, int n_in,
                              void* d_out, int out_size, void* d_ws, size_t ws_size,
                              hipStream_t stream)
{
    const float* memory      = (const float*)d_in[0];
    const int*   last_update = (const int*)d_in[1];
    const int*   src         = (const int*)d_in[2];
    const int*   dst         = (const int*)d_in[3];
    const int*   t           = (const int*)d_in[4];
    const float* raw_msg     = (const float*)d_in[5];
    const float* time_w      = (const float*)d_in[6];
    const float* time_b      = (const float*)d_in[7];
    const float* W_ih        = (const float*)d_in[8];
    const float* W_hh        = (const float*)d_in[9];
    const float* b_ih        = (const float*)d_in[10];
    const float* b_hh        = (const float*)d_in[11];

    const int n_nodes  = in_sizes[0] / MEMD;
    const int n_events = in_sizes[2];

    // Workspace layout: ACC(bf16) | cnt | lu | Wb | memB
    short* ACC = (short*)d_ws;
    int*   cnt = (int*)((char*)d_ws + (size_t)n_nodes * ACCD * sizeof(short));
    int*   lu  = cnt + n_nodes;
    bf16x8* Wb = (bf16x8*)(lu + n_nodes);
    short* memB = (short*)(Wb + GI_SLOTS + GH_SLOTS);

    const size_t zero_bytes = (size_t)n_nodes * ACCD * sizeof(short) + 2 * (size_t)n_nodes * sizeof(int);
    (void)hipMemsetAsync(d_ws, 0, zero_bytes, stream);

    tgn_prep_w<<<dim3((GI_SLOTS + GH_SLOTS + 255) / 256), dim3(256), 0, stream>>>(W_ih, W_hh, Wb);

    const int n8 = n_nodes * MEMD / 8;
    tgn_prep_mem<<<dim3((n8 + 255) / 256), dim3(256), 0, stream>>>(memory, memB, n8);

    tgn_scatter<<<dim3((n_events + 3) / 4), dim3(256), 0, stream>>>(
        memB, last_update, src, dst, t, raw_msg, time_w, time_b,
        ACC, cnt, lu, n_events);

    tgn_gru_mfma<<<dim3((n_nodes + 63) / 64), dim3(512), 0, stream>>>(
        memB, ACC, cnt, Wb, b_ih, b_hh, (float*)d_out, n_nodes);

    float* out2 = (float*)d_out + (size_t)n_nodes * MEMD;
    tgn_lu_out<<<dim3((n_nodes + 255) / 256), dim3(256), 0, stream>>>(lu, out2, n_nodes);
}

// Round 12
// 517.706 us; speedup vs baseline: 1.0383x; 1.0383x over previous
//
#include <hip/hip_runtime.h>
#include <cstdint>

// TGN memory update: message scatter-mean (bf16 packed atomics) + MFMA GRU.
// Round 12: M=96 (6 M-frags/wave) — tests weight-stream-bound hypothesis.
// R11 structure otherwise: reg-streamed weights (e/o dbuf), no loop barriers.

#define MEMD 128
#define ACCD 384
#define MSGD 512

typedef __attribute__((ext_vector_type(8))) short bf16x8;
typedef __attribute__((ext_vector_type(2))) short bf16x2;
typedef __attribute__((ext_vector_type(4))) float f32x4;

static __device__ __forceinline__ short f2bf(float f) {
    uint32_t u = __builtin_bit_cast(uint32_t, f);
    u = (u + 0x7FFFu + ((u >> 16) & 1u)) >> 16;
    return (short)u;
}
static __device__ __forceinline__ float bf2f(short s) {
    return __builtin_bit_cast(float, ((uint32_t)(uint16_t)s) << 16);
}
static __device__ __forceinline__ void atomic_pk_add_bf16(short* p, bf16x2 v) {
    const uint64_t addr = (uint64_t)p;
    asm volatile("global_atomic_pk_add_bf16 %0, %1, off" :: "v"(addr), "v"(v) : "memory");
}

// ---------------- Prep A: memory f32 -> bf16 ----------------
__global__ __launch_bounds__(256) void tgn_prep_mem(
    const float* __restrict__ mem, short* __restrict__ memB, int n8)
{
    const int i = blockIdx.x * 256 + threadIdx.x;
    if (i >= n8) return;
    const float4 a = *reinterpret_cast<const float4*>(mem + (size_t)i * 8);
    const float4 b = *reinterpret_cast<const float4*>(mem + (size_t)i * 8 + 4);
    bf16x8 v;
    v[0] = f2bf(a.x); v[1] = f2bf(a.y); v[2] = f2bf(a.z); v[3] = f2bf(a.w);
    v[4] = f2bf(b.x); v[5] = f2bf(b.y); v[6] = f2bf(b.z); v[7] = f2bf(b.w);
    *reinterpret_cast<bf16x8*>(memB + (size_t)i * 8) = v;
}

// ---------------- Prep B: weights f32 -> bf16 frag-major ----------------
// Wb: gi frags [24 ntile][16 kstep][64 lane], then gh frags [24][4][64].
// Frag (n,ks,lane): j = n*16 + (lane&15), k = ks*32 + (lane>>4)*8 .. +7.
#define GI_SLOTS (24 * 16 * 64)
#define GH_SLOTS (24 * 4 * 64)

__global__ __launch_bounds__(256) void tgn_prep_w(
    const float* __restrict__ W_ih, const float* __restrict__ W_hh,
    bf16x8* __restrict__ Wb)
{
    const int s = blockIdx.x * 256 + threadIdx.x;
    if (s >= GI_SLOTS + GH_SLOTS) return;
    const float* src;
    if (s < GI_SLOTS) {
        const int n = s / (16 * 64), rem = s % (16 * 64);
        const int ks = rem / 64, l = rem % 64;
        const int j = n * 16 + (l & 15), k = ks * 32 + (l >> 4) * 8;
        src = W_ih + (size_t)j * MSGD + k;
    } else {
        const int s2 = s - GI_SLOTS;
        const int n = s2 / (4 * 64), rem = s2 % (4 * 64);
        const int ks = rem / 64, l = rem % 64;
        const int j = n * 16 + (l & 15), k = ks * 32 + (l >> 4) * 8;
        src = W_hh + (size_t)j * MEMD + k;
    }
    bf16x8 v;
    #pragma unroll
    for (int e = 0; e < 8; ++e) v[e] = f2bf(src[e]);
    Wb[s] = v;
}

// ---------------- Phase 1: per-event scatter (packed bf16 atomics) --------
__global__ __launch_bounds__(256) void tgn_scatter(
    const short* __restrict__ memB, const int* __restrict__ last_update,
    const int* __restrict__ src, const int* __restrict__ dst, const int* __restrict__ t,
    const float* __restrict__ raw_msg, const float* __restrict__ time_w,
    const float* __restrict__ time_b,
    short* __restrict__ ACC, int* __restrict__ cnt, int* __restrict__ lu_new,
    int n_events)
{
    const int e = blockIdx.x * 4 + (threadIdx.x >> 6);
    if (e >= n_events) return;
    const int l = threadIdx.x & 63;
    const int j0 = l * 2;

    const int s = src[e];
    const int d = dst[e];
    const int te = t[e];

    const float2 tw = *reinterpret_cast<const float2*>(time_w + j0);
    const float2 tb = *reinterpret_cast<const float2*>(time_b + j0);
    const float dts = (float)(te - last_update[s]);
    const float dtd = (float)(te - last_update[d]);
    bf16x2 tenc_s, tenc_d, rb;
    tenc_s[0] = f2bf(__cosf(fmaf(dts, tw.x, tb.x)));
    tenc_s[1] = f2bf(__cosf(fmaf(dts, tw.y, tb.y)));
    tenc_d[0] = f2bf(__cosf(fmaf(dtd, tw.x, tb.x)));
    tenc_d[1] = f2bf(__cosf(fmaf(dtd, tw.y, tb.y)));

    const bf16x2 ms2 = *reinterpret_cast<const bf16x2*>(memB + (size_t)s * MEMD + j0);
    const bf16x2 md2 = *reinterpret_cast<const bf16x2*>(memB + (size_t)d * MEMD + j0);
    const float2 rw = *reinterpret_cast<const float2*>(raw_msg + (size_t)e * MEMD + j0);
    rb[0] = f2bf(rw.x); rb[1] = f2bf(rw.y);

    short* As = ACC + (size_t)s * ACCD;
    short* Ad = ACC + (size_t)d * ACCD;
    atomic_pk_add_bf16(As + j0, md2);
    atomic_pk_add_bf16(As + 128 + j0, rb);
    atomic_pk_add_bf16(As + 256 + j0, tenc_s);
    atomic_pk_add_bf16(Ad + j0, ms2);
    atomic_pk_add_bf16(Ad + 128 + j0, rb);
    atomic_pk_add_bf16(Ad + 256 + j0, tenc_d);

    if (l == 0) {
        atomicAdd(cnt + s, 1);
        atomicAdd(cnt + d, 1);
        atomicMax(lu_new + s, te);
        atomicMax(lu_new + d, te);
    }
}

// ---------------- Phase 2: MFMA GEMM + GRU (M=96, free-running waves) -----
// 512 threads (8 waves), 96 nodes/block, 96 KB LDS (Xf only).
// Wave wv owns N-tile triple {wv, wv+8, wv+16}; 6 M-frags; B streamed
// L2->VGPR with even/odd buffers; no block sync in the main loop.
#define MFMA18(ACCA, BV)                                                              \
    ACCA[0] = __builtin_amdgcn_mfma_f32_16x16x32_bf16(a0, BV, ACCA[0], 0, 0, 0);      \
    ACCA[1] = __builtin_amdgcn_mfma_f32_16x16x32_bf16(a1, BV, ACCA[1], 0, 0, 0);      \
    ACCA[2] = __builtin_amdgcn_mfma_f32_16x16x32_bf16(a2, BV, ACCA[2], 0, 0, 0);      \
    ACCA[3] = __builtin_amdgcn_mfma_f32_16x16x32_bf16(a3, BV, ACCA[3], 0, 0, 0);      \
    ACCA[4] = __builtin_amdgcn_mfma_f32_16x16x32_bf16(a4, BV, ACCA[4], 0, 0, 0);      \
    ACCA[5] = __builtin_amdgcn_mfma_f32_16x16x32_bf16(a5, BV, ACCA[5], 0, 0, 0);

#define LOAD_A(KS)                                        \
    const bf16x8 a0 = Xf[(0 * 16 + (KS)) * 64 + lane];    \
    const bf16x8 a1 = Xf[(1 * 16 + (KS)) * 64 + lane];    \
    const bf16x8 a2 = Xf[(2 * 16 + (KS)) * 64 + lane];    \
    const bf16x8 a3 = Xf[(3 * 16 + (KS)) * 64 + lane];    \
    const bf16x8 a4 = Xf[(4 * 16 + (KS)) * 64 + lane];    \
    const bf16x8 a5 = Xf[(5 * 16 + (KS)) * 64 + lane];

__global__ __launch_bounds__(512, 2) void tgn_gru_mfma(
    const short* __restrict__ memB, const short* __restrict__ ACC,
    const int* __restrict__ cnt, const bf16x8* __restrict__ Wb,
    const float* __restrict__ b_ih, const float* __restrict__ b_hh,
    float* __restrict__ out, int n_nodes)
{
    __shared__ bf16x8 Xf[6 * 16 * 64];      // 96 KB : X tile (frag-major)
    ushort* Xh = reinterpret_cast<ushort*>(Xf);
    float*  Sout = reinterpret_cast<float*>(Xf);   // reused after mv reads

    const int tid = threadIdx.x;
    const int lane = tid & 63;
    const int wv = tid >> 6;                 // wave id 0..7 (uniform)
    const int node0 = blockIdx.x * 96;

    // ---- stage X tile: 12 slots/thread, loads batched then converted ----
    bf16x8 sraw[12];
    float  sinv[12];
    #pragma unroll
    for (int i = 0; i < 12; ++i) {
        const int slot = i * 512 + tid;      // 0..6143
        const int l = slot & 63;
        const int ks = (slot >> 6) & 15;
        const int m = slot >> 10;            // 0..5
        int node = node0 + m * 16 + (l & 15);
        if (node >= n_nodes) node = n_nodes - 1;
        const int kbase = ks * 32 + (l >> 4) * 8;
        if (kbase < 128) {
            sraw[i] = *reinterpret_cast<const bf16x8*>(memB + (size_t)node * MEMD + kbase);
            sinv[i] = -1.0f;
        } else {
            sraw[i] = *reinterpret_cast<const bf16x8*>(ACC + (size_t)node * ACCD + (kbase - 128));
            const int c = cnt[node];
            sinv[i] = (c > 0) ? 1.0f / (float)c : 0.0f;
        }
    }
    #pragma unroll
    for (int i = 0; i < 12; ++i) {
        const int slot = i * 512 + tid;
        bf16x8 xv = sraw[i];
        if (sinv[i] >= 0.0f) {
            #pragma unroll
            for (int e2 = 0; e2 < 8; ++e2) xv[e2] = f2bf(bf2f(xv[e2]) * sinv[i]);
        }
        Xf[slot] = xv;
    }
    __syncthreads();   // X visible; waves run free from here

    const int col = lane & 15;
    const int rgrp = lane >> 4;

    f32x4 acc_i[3][6], acc_h[3][6];
    #pragma unroll
    for (int c = 0; c < 3; ++c)
        #pragma unroll
        for (int m = 0; m < 6; ++m) {
            acc_i[c][m] = (f32x4){0.f, 0.f, 0.f, 0.f};
            acc_h[c][m] = (f32x4){0.f, 0.f, 0.f, 0.f};
        }

    const bf16x8* __restrict__ Wh = Wb + GI_SLOTS;
    const int n0 = wv, n1 = wv + 8, n2 = wv + 16;

    bf16x8 e0, e1, e2, o0, o1, o2;
    e0 = Wh[(n0 * 4 + 0) * 64 + lane];
    e1 = Wh[(n1 * 4 + 0) * 64 + lane];
    e2 = Wh[(n2 * 4 + 0) * 64 + lane];

    // ---- gh: K=128, k-steps 0..3 ----
    #pragma unroll
    for (int kp = 0; kp < 2; ++kp) {
        const int ks = kp * 2;
        o0 = Wh[(n0 * 4 + ks + 1) * 64 + lane];
        o1 = Wh[(n1 * 4 + ks + 1) * 64 + lane];
        o2 = Wh[(n2 * 4 + ks + 1) * 64 + lane];
        {
            LOAD_A(ks)
            MFMA18(acc_h[0], e0)
            MFMA18(acc_h[1], e1)
            MFMA18(acc_h[2], e2)
        }
        if (ks + 2 < 4) {
            e0 = Wh[(n0 * 4 + ks + 2) * 64 + lane];
            e1 = Wh[(n1 * 4 + ks + 2) * 64 + lane];
            e2 = Wh[(n2 * 4 + ks + 2) * 64 + lane];
        } else {
            e0 = Wb[(n0 * 16 + 0) * 64 + lane];
            e1 = Wb[(n1 * 16 + 0) * 64 + lane];
            e2 = Wb[(n2 * 16 + 0) * 64 + lane];
        }
        {
            LOAD_A(ks + 1)
            MFMA18(acc_h[0], o0)
            MFMA18(acc_h[1], o1)
            MFMA18(acc_h[2], o2)
        }
    }

    // ---- gi: K=512, k-steps 0..15 (e* holds ks0) ----
    #pragma unroll
    for (int kp = 0; kp < 8; ++kp) {
        const int ks = kp * 2;
        o0 = Wb[(n0 * 16 + ks + 1) * 64 + lane];
        o1 = Wb[(n1 * 16 + ks + 1) * 64 + lane];
        o2 = Wb[(n2 * 16 + ks + 1) * 64 + lane];
        {
            LOAD_A(ks)
            MFMA18(acc_i[0], e0)
            MFMA18(acc_i[1], e1)
            MFMA18(acc_i[2], e2)
        }
        if (ks + 2 < 16) {
            e0 = Wb[(n0 * 16 + ks + 2) * 64 + lane];
            e1 = Wb[(n1 * 16 + ks + 2) * 64 + lane];
            e2 = Wb[(n2 * 16 + ks + 2) * 64 + lane];
        }
        {
            LOAD_A(ks + 1)
            MFMA18(acc_i[0], o0)
            MFMA18(acc_i[1], o1)
            MFMA18(acc_i[2], o2)
        }
    }

    // ---- GRU epilogue: wave-local triple (j, j+128, j+256) ----
    uint32_t hmask = 0;
    #pragma unroll
    for (int m = 0; m < 6; ++m)
        #pragma unroll
        for (int r = 0; r < 4; ++r) {
            const int node = node0 + m * 16 + rgrp * 4 + r;
            if (node < n_nodes && cnt[node] > 0) hmask |= 1u << (m * 4 + r);
        }

    const int jr = wv * 16 + col;            // 0..127
    const float bir = b_ih[jr], biz = b_ih[jr + 128], bin = b_ih[jr + 256];
    const float bhr = b_hh[jr], bhz = b_hh[jr + 128], bhn = b_hh[jr + 256];
    const int ksj = jr >> 5;
    const int sub = ((jr >> 3) & 3) * 16;
    const int elem = jr & 7;

    float rout[6][4];
    #pragma unroll
    for (int m = 0; m < 6; ++m) {
        #pragma unroll
        for (int r = 0; r < 4; ++r) {
            const bool has = (hmask >> (m * 4 + r)) & 1;
            const float gir = (has ? acc_i[0][m][r] : 0.f) + bir;
            const float giz = (has ? acc_i[1][m][r] : 0.f) + biz;
            const float gin = (has ? acc_i[2][m][r] : 0.f) + bin;
            const float ghr = acc_h[0][m][r] + bhr;
            const float ghz = acc_h[1][m][r] + bhz;
            const float ghn = acc_h[2][m][r] + bhn;
            const float rr = __fdividef(1.0f, 1.0f + __expf(-(gir + ghr)));
            const float zz = __fdividef(1.0f, 1.0f + __expf(-(giz + ghz)));
            const float targ = fmaf(rr, ghn, gin);
            const float e2v = __expf(2.0f * targ);
            const float nn = __fdividef(e2v - 1.0f, e2v + 1.0f);
            const int slot = (m * 16 + ksj) * 64 + sub + (rgrp * 4 + r);
            const float mv = bf2f((short)Xh[slot * 8 + elem]);
            rout[m][r] = (1.0f - zz) * nn + zz * mv;
        }
    }
    __syncthreads();   // all waves done with Xf (mv) -> reuse as Sout

    #pragma unroll
    for (int m = 0; m < 6; ++m)
        #pragma unroll
        for (int r = 0; r < 4; ++r)
            Sout[(m * 16 + rgrp * 4 + r) * MEMD + jr] = rout[m][r];
    __syncthreads();

    // ---- fully-coalesced float4 write-out (96 nodes x 128 f32) ----
    float4* out4 = reinterpret_cast<float4*>(out + (size_t)node0 * MEMD);
    const float4* S4 = reinterpret_cast<const float4*>(Sout);
    if (node0 + 96 <= n_nodes) {
        #pragma unroll
        for (int it = 0; it < 6; ++it)
            out4[it * 512 + tid] = S4[it * 512 + tid];
    } else {
        #pragma unroll
        for (int it = 0; it < 6; ++it) {
            const int idx = it * 512 + tid;
            if (node0 + (idx >> 5) < n_nodes) out4[idx] = S4[idx];
        }
    }
}

// ---------------- Phase 3: last_update -> float out ----------------
__global__ void tgn_lu_out(const int* __restrict__ lu, float* __restrict__ out2, int n_nodes)
{
    const int i = blockIdx.x * blockDim.x + threadIdx.x;
    if (i < n_nodes) out2[i] = (float)lu[i];
}

extern "C" void kernel_launch(void* const* d_in, const int* in_sizes, int n_in,
                              void* d_out, int out_size, void* d_ws, size_t ws_size,
                              hipStream_t stream)
{
    const float* memory      = (const float*)d_in[0];
    const int*   last_update = (const int*)d_in[1];
    const int*   src         = (const int*)d_in[2];
    const int*   dst         = (const int*)d_in[3];
    const int*   t           = (const int*)d_in[4];
    const float* raw_msg     = (const float*)d_in[5];
    const float* time_w      = (const float*)d_in[6];
    const float* time_b      = (const float*)d_in[7];
    const float* W_ih        = (const float*)d_in[8];
    const float* W_hh        = (const float*)d_in[9];
    const float* b_ih        = (const float*)d_in[10];
    const float* b_hh        = (const float*)d_in[11];

    const int n_nodes  = in_sizes[0] / MEMD;
    const int n_events = in_sizes[2];

    // Workspace layout: ACC(bf16) | cnt | lu | Wb | memB
    short* ACC = (short*)d_ws;
    int*   cnt = (int*)((char*)d_ws + (size_t)n_nodes * ACCD * sizeof(short));
    int*   lu  = cnt + n_nodes;
    bf16x8* Wb = (bf16x8*)(lu + n_nodes);
    short* memB = (short*)(Wb + GI_SLOTS + GH_SLOTS);

    const size_t zero_bytes = (size_t)n_nodes * ACCD * sizeof(short) + 2 * (size_t)n_nodes * sizeof(int);
    (void)hipMemsetAsync(d_ws, 0, zero_bytes, stream);

    tgn_prep_w<<<dim3((GI_SLOTS + GH_SLOTS + 255) / 256), dim3(256), 0, stream>>>(W_ih, W_hh, Wb);

    const int n8 = n_nodes * MEMD / 8;
    tgn_prep_mem<<<dim3((n8 + 255) / 256), dim3(256), 0, stream>>>(memory, memB, n8);

    tgn_scatter<<<dim3((n_events + 3) / 4), dim3(256), 0, stream>>>(
        memB, last_update, src, dst, t, raw_msg, time_w, time_b,
        ACC, cnt, lu, n_events);

    tgn_gru_mfma<<<dim3((n_nodes + 95) / 96), dim3(512), 0, stream>>>(
        memB, ACC, cnt, Wb, b_ih, b_hh, (float*)d_out, n_nodes);

    float* out2 = (float*)d_out + (size_t)n_nodes * MEMD;
    tgn_lu_out<<<dim3((n_nodes + 255) / 256), dim3(256), 0, stream>>>(lu, out2, n_nodes);
}

// Round 13
// 395.317 us; speedup vs baseline: 1.3597x; 1.3096x over previous
//
#include <hip/hip_runtime.h>
#include <cstdint>

// TGN memory update — round 13: linked-list gather aggregation (no f32/bf16
// atomics, no big memset, mean formed in f32 regs), gru staging via
// global_load_lds pure copy. GRU main loop = R12 (M=96, reg-streamed W).

#define MEMD 128
#define ACCD 384
#define MSGD 512

typedef __attribute__((ext_vector_type(8))) short bf16x8;
typedef __attribute__((ext_vector_type(2))) short bf16x2;
typedef __attribute__((ext_vector_type(4))) float f32x4;

static __device__ __forceinline__ short f2bf(float f) {
    uint32_t u = __builtin_bit_cast(uint32_t, f);
    u = (u + 0x7FFFu + ((u >> 16) & 1u)) >> 16;
    return (short)u;
}
static __device__ __forceinline__ float bf2f(short s) {
    return __builtin_bit_cast(float, ((uint32_t)(uint16_t)s) << 16);
}
// async 16B global->LDS; LDS dest = wave-uniform base + lane*16, global per-lane
static __device__ __forceinline__ void load_lds16(const void* g, void* l) {
    __builtin_amdgcn_global_load_lds(
        (const __attribute__((address_space(1))) unsigned int*)g,
        (__attribute__((address_space(3))) unsigned int*)l,
        16, 0, 0);
}

// ---------------- Prep A: memory f32 -> bf16 ----------------
__global__ __launch_bounds__(256) void tgn_prep_mem(
    const float* __restrict__ mem, short* __restrict__ memB, int n8)
{
    const int i = blockIdx.x * 256 + threadIdx.x;
    if (i >= n8) return;
    const float4 a = *reinterpret_cast<const float4*>(mem + (size_t)i * 8);
    const float4 b = *reinterpret_cast<const float4*>(mem + (size_t)i * 8 + 4);
    bf16x8 v;
    v[0] = f2bf(a.x); v[1] = f2bf(a.y); v[2] = f2bf(a.z); v[3] = f2bf(a.w);
    v[4] = f2bf(b.x); v[5] = f2bf(b.y); v[6] = f2bf(b.z); v[7] = f2bf(b.w);
    *reinterpret_cast<bf16x8*>(memB + (size_t)i * 8) = v;
}

// ---------------- Prep B: weights f32 -> bf16 frag-major ----------------
#define GI_SLOTS (24 * 16 * 64)
#define GH_SLOTS (24 * 4 * 64)

__global__ __launch_bounds__(256) void tgn_prep_w(
    const float* __restrict__ W_ih, const float* __restrict__ W_hh,
    bf16x8* __restrict__ Wb)
{
    const int s = blockIdx.x * 256 + threadIdx.x;
    if (s >= GI_SLOTS + GH_SLOTS) return;
    const float* src;
    if (s < GI_SLOTS) {
        const int n = s / (16 * 64), rem = s % (16 * 64);
        const int ks = rem / 64, l = rem % 64;
        const int j = n * 16 + (l & 15), k = ks * 32 + (l >> 4) * 8;
        src = W_ih + (size_t)j * MSGD + k;
    } else {
        const int s2 = s - GI_SLOTS;
        const int n = s2 / (4 * 64), rem = s2 % (4 * 64);
        const int ks = rem / 64, l = rem % 64;
        const int j = n * 16 + (l & 15), k = ks * 32 + (l >> 4) * 8;
        src = W_hh + (size_t)j * MEMD + k;
    }
    bf16x8 v;
    #pragma unroll
    for (int e = 0; e < 8; ++e) v[e] = f2bf(src[e]);
    Wb[s] = v;
}

// ---------------- Phase 1a: build per-node linked lists ----------------
// entry k = 2*e + dir; dir=0 -> list of src[e] (other=dst), dir=1 -> dst.
__global__ __launch_bounds__(256) void tgn_fill(
    const int* __restrict__ src, const int* __restrict__ dst, const int* __restrict__ t,
    int* __restrict__ head, int* __restrict__ nxt, int* __restrict__ lu_new,
    int n_events)
{
    const int e = blockIdx.x * 256 + threadIdx.x;
    if (e >= n_events) return;
    const int s = src[e];
    const int d = dst[e];
    const int te = t[e];
    nxt[2 * e]     = atomicExch(head + s, 2 * e);
    nxt[2 * e + 1] = atomicExch(head + d, 2 * e + 1);
    atomicMax(lu_new + s, te);
    atomicMax(lu_new + d, te);
}

// ---------------- Phase 1b: per-node gather-mean ----------------
// One wave per node; lane owns 2 dims of each 128-part. Mean in f32 regs,
// ACC row written once as bf16 (pre-divided).
__global__ __launch_bounds__(256) void tgn_aggregate(
    const int* __restrict__ head, const int* __restrict__ nxt,
    const int* __restrict__ src, const int* __restrict__ dst, const int* __restrict__ t,
    const float* __restrict__ raw_msg, const short* __restrict__ memB,
    const int* __restrict__ last_update,
    const float* __restrict__ time_w, const float* __restrict__ time_b,
    short* __restrict__ ACC, int n_nodes)
{
    const int n = blockIdx.x * 4 + (threadIdx.x >> 6);
    if (n >= n_nodes) return;
    int k = head[n];
    if (k < 0) return;                       // no events: gru gates via head
    const int lane = threadIdx.x & 63;
    const int j0 = lane * 2;

    const float lus = (float)last_update[n];
    const float2 tw = *reinterpret_cast<const float2*>(time_w + j0);
    const float2 tb = *reinterpret_cast<const float2*>(time_b + j0);

    float am0 = 0.f, am1 = 0.f, ar0 = 0.f, ar1 = 0.f, at0 = 0.f, at1 = 0.f;
    int c = 0;
    while (k >= 0) {
        const int kn = nxt[k];               // issue chase early
        const int e = k >> 1;
        const int other = (k & 1) ? src[e] : dst[e];
        const float te = (float)t[e];
        const float2 rw = *reinterpret_cast<const float2*>(raw_msg + (size_t)e * MEMD + j0);
        const bf16x2 mb = *reinterpret_cast<const bf16x2*>(memB + (size_t)other * MEMD + j0);
        const float dt = te - lus;
        at0 += __cosf(fmaf(dt, tw.x, tb.x));
        at1 += __cosf(fmaf(dt, tw.y, tb.y));
        ar0 += rw.x; ar1 += rw.y;
        am0 += bf2f(mb[0]); am1 += bf2f(mb[1]);
        ++c;
        k = kn;
    }
    const float inv = 1.0f / (float)c;
    short* row = ACC + (size_t)n * ACCD;
    bf16x2 v;
    v[0] = f2bf(am0 * inv); v[1] = f2bf(am1 * inv);
    *reinterpret_cast<bf16x2*>(row + j0) = v;
    v[0] = f2bf(ar0 * inv); v[1] = f2bf(ar1 * inv);
    *reinterpret_cast<bf16x2*>(row + 128 + j0) = v;
    v[0] = f2bf(at0 * inv); v[1] = f2bf(at1 * inv);
    *reinterpret_cast<bf16x2*>(row + 256 + j0) = v;
}

// ---------------- Phase 2: MFMA GEMM + GRU (M=96, free-running waves) -----
#define MFMA18(ACCA, BV)                                                              \
    ACCA[0] = __builtin_amdgcn_mfma_f32_16x16x32_bf16(a0, BV, ACCA[0], 0, 0, 0);      \
    ACCA[1] = __builtin_amdgcn_mfma_f32_16x16x32_bf16(a1, BV, ACCA[1], 0, 0, 0);      \
    ACCA[2] = __builtin_amdgcn_mfma_f32_16x16x32_bf16(a2, BV, ACCA[2], 0, 0, 0);      \
    ACCA[3] = __builtin_amdgcn_mfma_f32_16x16x32_bf16(a3, BV, ACCA[3], 0, 0, 0);      \
    ACCA[4] = __builtin_amdgcn_mfma_f32_16x16x32_bf16(a4, BV, ACCA[4], 0, 0, 0);      \
    ACCA[5] = __builtin_amdgcn_mfma_f32_16x16x32_bf16(a5, BV, ACCA[5], 0, 0, 0);

#define LOAD_A(KS)                                        \
    const bf16x8 a0 = Xf[(0 * 16 + (KS)) * 64 + lane];    \
    const bf16x8 a1 = Xf[(1 * 16 + (KS)) * 64 + lane];    \
    const bf16x8 a2 = Xf[(2 * 16 + (KS)) * 64 + lane];    \
    const bf16x8 a3 = Xf[(3 * 16 + (KS)) * 64 + lane];    \
    const bf16x8 a4 = Xf[(4 * 16 + (KS)) * 64 + lane];    \
    const bf16x8 a5 = Xf[(5 * 16 + (KS)) * 64 + lane];

__global__ __launch_bounds__(512, 2) void tgn_gru_mfma(
    const short* __restrict__ memB, const short* __restrict__ ACC,
    const int* __restrict__ head, const bf16x8* __restrict__ Wb,
    const float* __restrict__ b_ih, const float* __restrict__ b_hh,
    float* __restrict__ out, int n_nodes)
{
    __shared__ bf16x8 Xf[6 * 16 * 64];      // 96 KB : X tile (frag-major)
    ushort* Xh = reinterpret_cast<ushort*>(Xf);
    float*  Sout = reinterpret_cast<float*>(Xf);   // reused after mv reads

    const int tid = threadIdx.x;
    const int lane = tid & 63;
    const int wv = tid >> 6;                 // wave id 0..7 (uniform)
    const int node0 = blockIdx.x * 96;

    // ---- stage X tile: pure async copy (no VALU convert, pre-divided ACC) --
    #pragma unroll
    for (int i = 0; i < 12; ++i) {
        const int slotbase = i * 512 + (tid & ~63);   // wave-uniform
        const int slot = slotbase + lane;
        const int ks = (slot >> 6) & 15;              // lane-independent
        const int m = slot >> 10;                     // lane-independent
        int node = node0 + m * 16 + (lane & 15);
        if (node >= n_nodes) node = n_nodes - 1;
        const int kbase = ks * 32 + (lane >> 4) * 8;
        const short* g = (kbase < 128)
            ? (memB + (size_t)node * MEMD + kbase)
            : (ACC + (size_t)node * ACCD + (kbase - 128));
        load_lds16(g, &Xf[slotbase]);
    }
    asm volatile("s_waitcnt vmcnt(0)" ::: "memory");
    __syncthreads();   // X visible; waves run free from here

    const int col = lane & 15;
    const int rgrp = lane >> 4;

    f32x4 acc_i[3][6], acc_h[3][6];
    #pragma unroll
    for (int c = 0; c < 3; ++c)
        #pragma unroll
        for (int m = 0; m < 6; ++m) {
            acc_i[c][m] = (f32x4){0.f, 0.f, 0.f, 0.f};
            acc_h[c][m] = (f32x4){0.f, 0.f, 0.f, 0.f};
        }

    const bf16x8* __restrict__ Wh = Wb + GI_SLOTS;
    const int n0 = wv, n1 = wv + 8, n2 = wv + 16;

    bf16x8 e0, e1, e2, o0, o1, o2;
    e0 = Wh[(n0 * 4 + 0) * 64 + lane];
    e1 = Wh[(n1 * 4 + 0) * 64 + lane];
    e2 = Wh[(n2 * 4 + 0) * 64 + lane];

    // ---- gh: K=128, k-steps 0..3 ----
    #pragma unroll
    for (int kp = 0; kp < 2; ++kp) {
        const int ks = kp * 2;
        o0 = Wh[(n0 * 4 + ks + 1) * 64 + lane];
        o1 = Wh[(n1 * 4 + ks + 1) * 64 + lane];
        o2 = Wh[(n2 * 4 + ks + 1) * 64 + lane];
        {
            LOAD_A(ks)
            MFMA18(acc_h[0], e0)
            MFMA18(acc_h[1], e1)
            MFMA18(acc_h[2], e2)
        }
        if (ks + 2 < 4) {
            e0 = Wh[(n0 * 4 + ks + 2) * 64 + lane];
            e1 = Wh[(n1 * 4 + ks + 2) * 64 + lane];
            e2 = Wh[(n2 * 4 + ks + 2) * 64 + lane];
        } else {
            e0 = Wb[(n0 * 16 + 0) * 64 + lane];
            e1 = Wb[(n1 * 16 + 0) * 64 + lane];
            e2 = Wb[(n2 * 16 + 0) * 64 + lane];
        }
        {
            LOAD_A(ks + 1)
            MFMA18(acc_h[0], o0)
            MFMA18(acc_h[1], o1)
            MFMA18(acc_h[2], o2)
        }
    }

    // ---- gi: K=512, k-steps 0..15 ----
    #pragma unroll
    for (int kp = 0; kp < 8; ++kp) {
        const int ks = kp * 2;
        o0 = Wb[(n0 * 16 + ks + 1) * 64 + lane];
        o1 = Wb[(n1 * 16 + ks + 1) * 64 + lane];
        o2 = Wb[(n2 * 16 + ks + 1) * 64 + lane];
        {
            LOAD_A(ks)
            MFMA18(acc_i[0], e0)
            MFMA18(acc_i[1], e1)
            MFMA18(acc_i[2], e2)
        }
        if (ks + 2 < 16) {
            e0 = Wb[(n0 * 16 + ks + 2) * 64 + lane];
            e1 = Wb[(n1 * 16 + ks + 2) * 64 + lane];
            e2 = Wb[(n2 * 16 + ks + 2) * 64 + lane];
        }
        {
            LOAD_A(ks + 1)
            MFMA18(acc_i[0], o0)
            MFMA18(acc_i[1], o1)
            MFMA18(acc_i[2], o2)
        }
    }

    // ---- GRU epilogue: wave-local triple (j, j+128, j+256) ----
    uint32_t hmask = 0;
    #pragma unroll
    for (int m = 0; m < 6; ++m)
        #pragma unroll
        for (int r = 0; r < 4; ++r) {
            const int node = node0 + m * 16 + rgrp * 4 + r;
            if (node < n_nodes && head[node] >= 0) hmask |= 1u << (m * 4 + r);
        }

    const int jr = wv * 16 + col;            // 0..127
    const float bir = b_ih[jr], biz = b_ih[jr + 128], bin = b_ih[jr + 256];
    const float bhr = b_hh[jr], bhz = b_hh[jr + 128], bhn = b_hh[jr + 256];
    const int ksj = jr >> 5;
    const int sub = ((jr >> 3) & 3) * 16;
    const int elem = jr & 7;

    float rout[6][4];
    #pragma unroll
    for (int m = 0; m < 6; ++m) {
        #pragma unroll
        for (int r = 0; r < 4; ++r) {
            const bool has = (hmask >> (m * 4 + r)) & 1;
            const float gir = (has ? acc_i[0][m][r] : 0.f) + bir;
            const float giz = (has ? acc_i[1][m][r] : 0.f) + biz;
            const float gin = (has ? acc_i[2][m][r] : 0.f) + bin;
            const float ghr = acc_h[0][m][r] + bhr;
            const float ghz = acc_h[1][m][r] + bhz;
            const float ghn = acc_h[2][m][r] + bhn;
            const float rr = __fdividef(1.0f, 1.0f + __expf(-(gir + ghr)));
            const float zz = __fdividef(1.0f, 1.0f + __expf(-(giz + ghz)));
            const float targ = fmaf(rr, ghn, gin);
            const float e2v = __expf(2.0f * targ);
            const float nn = __fdividef(e2v - 1.0f, e2v + 1.0f);
            const int slot = (m * 16 + ksj) * 64 + sub + (rgrp * 4 + r);
            const float mv = bf2f((short)Xh[slot * 8 + elem]);
            rout[m][r] = (1.0f - zz) * nn + zz * mv;
        }
    }
    __syncthreads();   // all waves done with Xf (mv) -> reuse as Sout

    #pragma unroll
    for (int m = 0; m < 6; ++m)
        #pragma unroll
        for (int r = 0; r < 4; ++r)
            Sout[(m * 16 + rgrp * 4 + r) * MEMD + jr] = rout[m][r];
    __syncthreads();

    // ---- fully-coalesced float4 write-out (96 nodes x 128 f32) ----
    float4* out4 = reinterpret_cast<float4*>(out + (size_t)node0 * MEMD);
    const float4* S4 = reinterpret_cast<const float4*>(Sout);
    if (node0 + 96 <= n_nodes) {
        #pragma unroll
        for (int it = 0; it < 6; ++it)
            out4[it * 512 + tid] = S4[it * 512 + tid];
    } else {
        #pragma unroll
        for (int it = 0; it < 6; ++it) {
            const int idx = it * 512 + tid;
            if (node0 + (idx >> 5) < n_nodes) out4[idx] = S4[idx];
        }
    }
}

// ---------------- Phase 3: last_update -> float out ----------------
__global__ void tgn_lu_out(const int* __restrict__ lu, float* __restrict__ out2, int n_nodes)
{
    const int i = blockIdx.x * blockDim.x + threadIdx.x;
    if (i < n_nodes) out2[i] = (float)lu[i];
}

extern "C" void kernel_launch(void* const* d_in, const int* in_sizes, int n_in,
                              void* d_out, int out_size, void* d_ws, size_t ws_size,
                              hipStream_t stream)
{
    const float* memory      = (const float*)d_in[0];
    const int*   last_update = (const int*)d_in[1];
    const int*   src         = (const int*)d_in[2];
    const int*   dst         = (const int*)d_in[3];
    const int*   t           = (const int*)d_in[4];
    const float* raw_msg     = (const float*)d_in[5];
    const float* time_w      = (const float*)d_in[6];
    const float* time_b      = (const float*)d_in[7];
    const float* W_ih        = (const float*)d_in[8];
    const float* W_hh        = (const float*)d_in[9];
    const float* b_ih        = (const float*)d_in[10];
    const float* b_hh        = (const float*)d_in[11];

    const int n_nodes  = in_sizes[0] / MEMD;
    const int n_events = in_sizes[2];

    // Workspace: ACC(bf16 means) | head | next | lu | Wb | memB
    short* ACC  = (short*)d_ws;
    int*   head = (int*)(ACC + (size_t)n_nodes * ACCD);
    int*   nxt  = head + n_nodes;
    int*   lu   = nxt + 2 * n_events;
    bf16x8* Wb  = (bf16x8*)(lu + n_nodes);
    short* memB = (short*)(Wb + GI_SLOTS + GH_SLOTS);

    (void)hipMemsetAsync(head, 0xFF, (size_t)n_nodes * sizeof(int), stream); // -1
    (void)hipMemsetAsync(lu, 0, (size_t)n_nodes * sizeof(int), stream);

    tgn_prep_w<<<dim3((GI_SLOTS + GH_SLOTS + 255) / 256), dim3(256), 0, stream>>>(W_ih, W_hh, Wb);

    const int n8 = n_nodes * MEMD / 8;
    tgn_prep_mem<<<dim3((n8 + 255) / 256), dim3(256), 0, stream>>>(memory, memB, n8);

    tgn_fill<<<dim3((n_events + 255) / 256), dim3(256), 0, stream>>>(
        src, dst, t, head, nxt, lu, n_events);

    tgn_aggregate<<<dim3((n_nodes + 3) / 4), dim3(256), 0, stream>>>(
        head, nxt, src, dst, t, raw_msg, memB, last_update, time_w, time_b,
        ACC, n_nodes);

    tgn_gru_mfma<<<dim3((n_nodes + 95) / 96), dim3(512), 0, stream>>>(
        memB, ACC, head, Wb, b_ih, b_hh, (float*)d_out, n_nodes);

    float* out2 = (float*)d_out + (size_t)n_nodes * MEMD;
    tgn_lu_out<<<dim3((n_nodes + 255) / 256), dim3(256), 0, stream>>>(lu, out2, n_nodes);
}

// Round 14
// 365.832 us; speedup vs baseline: 1.4693x; 1.0806x over previous
//
#include <hip/hip_runtime.h>
#include <cstdint>

// TGN memory update — round 14: occupancy via register diet.
// M=32, 512 threads, acc=48 regs/thread -> 4 waves/SIMD (2 blocks/CU).
// R13 structure otherwise: linked-list gather aggregation, pure-copy
// global_load_lds staging, reg-streamed weights (e/o dbuf), no loop barriers.

#define MEMD 128
#define ACCD 384
#define MSGD 512

typedef __attribute__((ext_vector_type(8))) short bf16x8;
typedef __attribute__((ext_vector_type(2))) short bf16x2;
typedef __attribute__((ext_vector_type(4))) float f32x4;

static __device__ __forceinline__ short f2bf(float f) {
    uint32_t u = __builtin_bit_cast(uint32_t, f);
    u = (u + 0x7FFFu + ((u >> 16) & 1u)) >> 16;
    return (short)u;
}
static __device__ __forceinline__ float bf2f(short s) {
    return __builtin_bit_cast(float, ((uint32_t)(uint16_t)s) << 16);
}
// async 16B global->LDS; LDS dest = wave-uniform base + lane*16, global per-lane
static __device__ __forceinline__ void load_lds16(const void* g, void* l) {
    __builtin_amdgcn_global_load_lds(
        (const __attribute__((address_space(1))) unsigned int*)g,
        (__attribute__((address_space(3))) unsigned int*)l,
        16, 0, 0);
}

// ---------------- Prep A: memory f32 -> bf16 ----------------
__global__ __launch_bounds__(256) void tgn_prep_mem(
    const float* __restrict__ mem, short* __restrict__ memB, int n8)
{
    const int i = blockIdx.x * 256 + threadIdx.x;
    if (i >= n8) return;
    const float4 a = *reinterpret_cast<const float4*>(mem + (size_t)i * 8);
    const float4 b = *reinterpret_cast<const float4*>(mem + (size_t)i * 8 + 4);
    bf16x8 v;
    v[0] = f2bf(a.x); v[1] = f2bf(a.y); v[2] = f2bf(a.z); v[3] = f2bf(a.w);
    v[4] = f2bf(b.x); v[5] = f2bf(b.y); v[6] = f2bf(b.z); v[7] = f2bf(b.w);
    *reinterpret_cast<bf16x8*>(memB + (size_t)i * 8) = v;
}

// ---------------- Prep B: weights f32 -> bf16 frag-major ----------------
#define GI_SLOTS (24 * 16 * 64)
#define GH_SLOTS (24 * 4 * 64)

__global__ __launch_bounds__(256) void tgn_prep_w(
    const float* __restrict__ W_ih, const float* __restrict__ W_hh,
    bf16x8* __restrict__ Wb)
{
    const int s = blockIdx.x * 256 + threadIdx.x;
    if (s >= GI_SLOTS + GH_SLOTS) return;
    const float* src;
    if (s < GI_SLOTS) {
        const int n = s / (16 * 64), rem = s % (16 * 64);
        const int ks = rem / 64, l = rem % 64;
        const int j = n * 16 + (l & 15), k = ks * 32 + (l >> 4) * 8;
        src = W_ih + (size_t)j * MSGD + k;
    } else {
        const int s2 = s - GI_SLOTS;
        const int n = s2 / (4 * 64), rem = s2 % (4 * 64);
        const int ks = rem / 64, l = rem % 64;
        const int j = n * 16 + (l & 15), k = ks * 32 + (l >> 4) * 8;
        src = W_hh + (size_t)j * MEMD + k;
    }
    bf16x8 v;
    #pragma unroll
    for (int e = 0; e < 8; ++e) v[e] = f2bf(src[e]);
    Wb[s] = v;
}

// ---------------- Phase 1a: build per-node linked lists ----------------
__global__ __launch_bounds__(256) void tgn_fill(
    const int* __restrict__ src, const int* __restrict__ dst, const int* __restrict__ t,
    int* __restrict__ head, int* __restrict__ nxt, int* __restrict__ lu_new,
    int n_events)
{
    const int e = blockIdx.x * 256 + threadIdx.x;
    if (e >= n_events) return;
    const int s = src[e];
    const int d = dst[e];
    const int te = t[e];
    nxt[2 * e]     = atomicExch(head + s, 2 * e);
    nxt[2 * e + 1] = atomicExch(head + d, 2 * e + 1);
    atomicMax(lu_new + s, te);
    atomicMax(lu_new + d, te);
}

// ---------------- Phase 1b: per-node gather-mean ----------------
__global__ __launch_bounds__(256) void tgn_aggregate(
    const int* __restrict__ head, const int* __restrict__ nxt,
    const int* __restrict__ src, const int* __restrict__ dst, const int* __restrict__ t,
    const float* __restrict__ raw_msg, const short* __restrict__ memB,
    const int* __restrict__ last_update,
    const float* __restrict__ time_w, const float* __restrict__ time_b,
    short* __restrict__ ACC, int n_nodes)
{
    const int n = blockIdx.x * 4 + (threadIdx.x >> 6);
    if (n >= n_nodes) return;
    int k = head[n];
    if (k < 0) return;                       // no events: gru gates via head
    const int lane = threadIdx.x & 63;
    const int j0 = lane * 2;

    const float lus = (float)last_update[n];
    const float2 tw = *reinterpret_cast<const float2*>(time_w + j0);
    const float2 tb = *reinterpret_cast<const float2*>(time_b + j0);

    float am0 = 0.f, am1 = 0.f, ar0 = 0.f, ar1 = 0.f, at0 = 0.f, at1 = 0.f;
    int c = 0;
    while (k >= 0) {
        const int kn = nxt[k];               // issue chase early
        const int e = k >> 1;
        const int other = (k & 1) ? src[e] : dst[e];
        const float te = (float)t[e];
        const float2 rw = *reinterpret_cast<const float2*>(raw_msg + (size_t)e * MEMD + j0);
        const bf16x2 mb = *reinterpret_cast<const bf16x2*>(memB + (size_t)other * MEMD + j0);
        const float dt = te - lus;
        at0 += __cosf(fmaf(dt, tw.x, tb.x));
        at1 += __cosf(fmaf(dt, tw.y, tb.y));
        ar0 += rw.x; ar1 += rw.y;
        am0 += bf2f(mb[0]); am1 += bf2f(mb[1]);
        ++c;
        k = kn;
    }
    const float inv = 1.0f / (float)c;
    short* row = ACC + (size_t)n * ACCD;
    bf16x2 v;
    v[0] = f2bf(am0 * inv); v[1] = f2bf(am1 * inv);
    *reinterpret_cast<bf16x2*>(row + j0) = v;
    v[0] = f2bf(ar0 * inv); v[1] = f2bf(ar1 * inv);
    *reinterpret_cast<bf16x2*>(row + 128 + j0) = v;
    v[0] = f2bf(at0 * inv); v[1] = f2bf(at1 * inv);
    *reinterpret_cast<bf16x2*>(row + 256 + j0) = v;
}

// ---------------- Phase 2: MFMA GEMM + GRU (M=32, 4 waves/SIMD) -----------
#define MFMA6(ACCA, BV)                                                               \
    ACCA[0] = __builtin_amdgcn_mfma_f32_16x16x32_bf16(a0, BV, ACCA[0], 0, 0, 0);      \
    ACCA[1] = __builtin_amdgcn_mfma_f32_16x16x32_bf16(a1, BV, ACCA[1], 0, 0, 0);

#define LOAD_A(KS)                                        \
    const bf16x8 a0 = Xf[(0 * 16 + (KS)) * 64 + lane];    \
    const bf16x8 a1 = Xf[(1 * 16 + (KS)) * 64 + lane];

__global__ __launch_bounds__(512, 4) void tgn_gru_mfma(
    const short* __restrict__ memB, const short* __restrict__ ACC,
    const int* __restrict__ head, const bf16x8* __restrict__ Wb,
    const float* __restrict__ b_ih, const float* __restrict__ b_hh,
    float* __restrict__ out, int n_nodes)
{
    __shared__ bf16x8 Xf[2 * 16 * 64];      // 32 KB : X tile (frag-major)
    ushort* Xh = reinterpret_cast<ushort*>(Xf);
    float*  Sout = reinterpret_cast<float*>(Xf);   // reused after mv reads

    const int tid = threadIdx.x;
    const int lane = tid & 63;
    const int wv = tid >> 6;                 // wave id 0..7 (uniform)
    const int node0 = blockIdx.x * 32;

    // ---- stage X tile: pure async copy ----
    #pragma unroll
    for (int i = 0; i < 4; ++i) {
        const int slotbase = i * 512 + (tid & ~63);   // wave-uniform
        const int slot = slotbase + lane;
        const int ks = (slot >> 6) & 15;              // lane-independent
        const int m = slot >> 10;                     // lane-independent (0..1)
        int node = node0 + m * 16 + (lane & 15);
        if (node >= n_nodes) node = n_nodes - 1;
        const int kbase = ks * 32 + (lane >> 4) * 8;
        const short* g = (kbase < 128)
            ? (memB + (size_t)node * MEMD + kbase)
            : (ACC + (size_t)node * ACCD + (kbase - 128));
        load_lds16(g, &Xf[slotbase]);
    }
    asm volatile("s_waitcnt vmcnt(0)" ::: "memory");
    __syncthreads();   // X visible; waves run free from here

    const int col = lane & 15;
    const int rgrp = lane >> 4;

    f32x4 acc_i[3][2], acc_h[3][2];
    #pragma unroll
    for (int c = 0; c < 3; ++c)
        #pragma unroll
        for (int m = 0; m < 2; ++m) {
            acc_i[c][m] = (f32x4){0.f, 0.f, 0.f, 0.f};
            acc_h[c][m] = (f32x4){0.f, 0.f, 0.f, 0.f};
        }

    const bf16x8* __restrict__ Wh = Wb + GI_SLOTS;
    const int n0 = wv, n1 = wv + 8, n2 = wv + 16;

    bf16x8 e0, e1, e2, o0, o1, o2;
    e0 = Wh[(n0 * 4 + 0) * 64 + lane];
    e1 = Wh[(n1 * 4 + 0) * 64 + lane];
    e2 = Wh[(n2 * 4 + 0) * 64 + lane];

    // ---- gh: K=128, k-steps 0..3 ----
    #pragma unroll
    for (int kp = 0; kp < 2; ++kp) {
        const int ks = kp * 2;
        o0 = Wh[(n0 * 4 + ks + 1) * 64 + lane];
        o1 = Wh[(n1 * 4 + ks + 1) * 64 + lane];
        o2 = Wh[(n2 * 4 + ks + 1) * 64 + lane];
        {
            LOAD_A(ks)
            MFMA6(acc_h[0], e0)
            MFMA6(acc_h[1], e1)
            MFMA6(acc_h[2], e2)
        }
        if (ks + 2 < 4) {
            e0 = Wh[(n0 * 4 + ks + 2) * 64 + lane];
            e1 = Wh[(n1 * 4 + ks + 2) * 64 + lane];
            e2 = Wh[(n2 * 4 + ks + 2) * 64 + lane];
        } else {
            e0 = Wb[(n0 * 16 + 0) * 64 + lane];
            e1 = Wb[(n1 * 16 + 0) * 64 + lane];
            e2 = Wb[(n2 * 16 + 0) * 64 + lane];
        }
        {
            LOAD_A(ks + 1)
            MFMA6(acc_h[0], o0)
            MFMA6(acc_h[1], o1)
            MFMA6(acc_h[2], o2)
        }
    }

    // ---- gi: K=512, k-steps 0..15 ----
    #pragma unroll
    for (int kp = 0; kp < 8; ++kp) {
        const int ks = kp * 2;
        o0 = Wb[(n0 * 16 + ks + 1) * 64 + lane];
        o1 = Wb[(n1 * 16 + ks + 1) * 64 + lane];
        o2 = Wb[(n2 * 16 + ks + 1) * 64 + lane];
        {
            LOAD_A(ks)
            MFMA6(acc_i[0], e0)
            MFMA6(acc_i[1], e1)
            MFMA6(acc_i[2], e2)
        }
        if (ks + 2 < 16) {
            e0 = Wb[(n0 * 16 + ks + 2) * 64 + lane];
            e1 = Wb[(n1 * 16 + ks + 2) * 64 + lane];
            e2 = Wb[(n2 * 16 + ks + 2) * 64 + lane];
        }
        {
            LOAD_A(ks + 1)
            MFMA6(acc_i[0], o0)
            MFMA6(acc_i[1], o1)
            MFMA6(acc_i[2], o2)
        }
    }

    // ---- GRU epilogue: wave-local triple (j, j+128, j+256) ----
    uint32_t hmask = 0;
    #pragma unroll
    for (int m = 0; m < 2; ++m)
        #pragma unroll
        for (int r = 0; r < 4; ++r) {
            const int node = node0 + m * 16 + rgrp * 4 + r;
            if (node < n_nodes && head[node] >= 0) hmask |= 1u << (m * 4 + r);
        }

    const int jr = wv * 16 + col;            // 0..127
    const float bir = b_ih[jr], biz = b_ih[jr + 128], bin = b_ih[jr + 256];
    const float bhr = b_hh[jr], bhz = b_hh[jr + 128], bhn = b_hh[jr + 256];
    const int ksj = jr >> 5;
    const int sub = ((jr >> 3) & 3) * 16;
    const int elem = jr & 7;

    float rout[2][4];
    #pragma unroll
    for (int m = 0; m < 2; ++m) {
        #pragma unroll
        for (int r = 0; r < 4; ++r) {
            const bool has = (hmask >> (m * 4 + r)) & 1;
            const float gir = (has ? acc_i[0][m][r] : 0.f) + bir;
            const float giz = (has ? acc_i[1][m][r] : 0.f) + biz;
            const float gin = (has ? acc_i[2][m][r] : 0.f) + bin;
            const float ghr = acc_h[0][m][r] + bhr;
            const float ghz = acc_h[1][m][r] + bhz;
            const float ghn = acc_h[2][m][r] + bhn;
            const float rr = __fdividef(1.0f, 1.0f + __expf(-(gir + ghr)));
            const float zz = __fdividef(1.0f, 1.0f + __expf(-(giz + ghz)));
            const float targ = fmaf(rr, ghn, gin);
            const float e2v = __expf(2.0f * targ);
            const float nn = __fdividef(e2v - 1.0f, e2v + 1.0f);
            const int slot = (m * 16 + ksj) * 64 + sub + (rgrp * 4 + r);
            const float mv = bf2f((short)Xh[slot * 8 + elem]);
            rout[m][r] = (1.0f - zz) * nn + zz * mv;
        }
    }
    __syncthreads();   // all waves done with Xf (mv) -> reuse as Sout

    #pragma unroll
    for (int m = 0; m < 2; ++m)
        #pragma unroll
        for (int r = 0; r < 4; ++r)
            Sout[(m * 16 + rgrp * 4 + r) * MEMD + jr] = rout[m][r];
    __syncthreads();

    // ---- fully-coalesced float4 write-out (32 nodes x 128 f32) ----
    float4* out4 = reinterpret_cast<float4*>(out + (size_t)node0 * MEMD);
    const float4* S4 = reinterpret_cast<const float4*>(Sout);
    if (node0 + 32 <= n_nodes) {
        #pragma unroll
        for (int it = 0; it < 2; ++it)
            out4[it * 512 + tid] = S4[it * 512 + tid];
    } else {
        #pragma unroll
        for (int it = 0; it < 2; ++it) {
            const int idx = it * 512 + tid;
            if (node0 + (idx >> 5) < n_nodes) out4[idx] = S4[idx];
        }
    }
}

// ---------------- Phase 3: last_update -> float out ----------------
__global__ void tgn_lu_out(const int* __restrict__ lu, float* __restrict__ out2, int n_nodes)
{
    const int i = blockIdx.x * blockDim.x + threadIdx.x;
    if (i < n_nodes) out2[i] = (float)lu[i];
}

extern "C" void kernel_launch(void* const* d_in, const int* in_sizes, int n_in,
                              void* d_out, int out_size, void* d_ws, size_t ws_size,
                              hipStream_t stream)
{
    const float* memory      = (const float*)d_in[0];
    const int*   last_update = (const int*)d_in[1];
    const int*   src         = (const int*)d_in[2];
    const int*   dst         = (const int*)d_in[3];
    const int*   t           = (const int*)d_in[4];
    const float* raw_msg     = (const float*)d_in[5];
    const float* time_w      = (const float*)d_in[6];
    const float* time_b      = (const float*)d_in[7];
    const float* W_ih        = (const float*)d_in[8];
    const float* W_hh        = (const float*)d_in[9];
    const float* b_ih        = (const float*)d_in[10];
    const float* b_hh        = (const float*)d_in[11];

    const int n_nodes  = in_sizes[0] / MEMD;
    const int n_events = in_sizes[2];

    // Workspace: ACC(bf16 means) | head | next | lu | Wb | memB
    short* ACC  = (short*)d_ws;
    int*   head = (int*)(ACC + (size_t)n_nodes * ACCD);
    int*   nxt  = head + n_nodes;
    int*   lu   = nxt + 2 * n_events;
    bf16x8* Wb  = (bf16x8*)(lu + n_nodes);
    short* memB = (short*)(Wb + GI_SLOTS + GH_SLOTS);

    (void)hipMemsetAsync(head, 0xFF, (size_t)n_nodes * sizeof(int), stream); // -1
    (void)hipMemsetAsync(lu, 0, (size_t)n_nodes * sizeof(int), stream);

    tgn_prep_w<<<dim3((GI_SLOTS + GH_SLOTS + 255) / 256), dim3(256), 0, stream>>>(W_ih, W_hh, Wb);

    const int n8 = n_nodes * MEMD / 8;
    tgn_prep_mem<<<dim3((n8 + 255) / 256), dim3(256), 0, stream>>>(memory, memB, n8);

    tgn_fill<<<dim3((n_events + 255) / 256), dim3(256), 0, stream>>>(
        src, dst, t, head, nxt, lu, n_events);

    tgn_aggregate<<<dim3((n_nodes + 3) / 4), dim3(256), 0, stream>>>(
        head, nxt, src, dst, t, raw_msg, memB, last_update, time_w, time_b,
        ACC, n_nodes);

    tgn_gru_mfma<<<dim3((n_nodes + 31) / 32), dim3(512), 0, stream>>>(
        memB, ACC, head, Wb, b_ih, b_hh, (float*)d_out, n_nodes);

    float* out2 = (float*)d_out + (size_t)n_nodes * MEMD;
    tgn_lu_out<<<dim3((n_nodes + 255) / 256), dim3(256), 0, stream>>>(lu, out2, n_nodes);
}